// Round 1
// baseline (9881.326 us; speedup 1.0000x reference)
//
#include <hip/hip_runtime.h>

typedef __attribute__((ext_vector_type(4))) float f32x4;
typedef __attribute__((ext_vector_type(8))) short bf16x8;

constexpr int kB = 32;    // batch
constexpr int kS = 2048;  // seq len
constexpr int kH = 256;   // hidden
constexpr int kG = 768;   // 3*H

__device__ __forceinline__ short f2bf(float f) {
  unsigned u = __builtin_bit_cast(unsigned, f);
  u += 0x7fffu + ((u >> 16) & 1u);  // RNE
  return (short)(u >> 16);
}

__device__ __forceinline__ float fast_sigmoid(float x) {
  float e = __builtin_amdgcn_exp2f(x * 1.4426950408889634f);
  return e * __builtin_amdgcn_rcpf(1.0f + e);
}
__device__ __forceinline__ float fast_tanh(float x) {
  float e = __builtin_amdgcn_exp2f(x * 2.8853900817779268f);  // e^(2x)
  return 1.0f - 2.0f * __builtin_amdgcn_rcpf(1.0f + e);
}

__device__ __forceinline__ void load8(const float* p, float v[8]) {
  const float4 a = *(const float4*)p;
  const float4 b = *(const float4*)(p + 4);
  v[0] = a.x; v[1] = a.y; v[2] = a.z; v[3] = a.w;
  v[4] = b.x; v[5] = b.y; v[6] = b.z; v[7] = b.w;
}
__device__ __forceinline__ void load8(const _Float16* p, float v[8]) {
  _Float16 t[8];
  *(uint4*)t = *(const uint4*)p;
#pragma unroll
  for (int j = 0; j < 8; ++j) v[j] = (float)t[j];
}

// gx[m=(s*32+b)][g] = sum_k A[b][s][k] * W[g][k] + b_ih[g] + (g<512 ? b_hh[g] : 0)
// A row length = K (256 for layer0 fp32 input, 512 for layer1 fp16 out0).
template <typename TIN>
__global__ __launch_bounds__(256) void gemm_gx(
    const TIN* __restrict__ A, const float* __restrict__ W,
    const float* __restrict__ b_ih, const float* __restrict__ b_hh,
    _Float16* __restrict__ gx, int K) {
  __shared__ short As[64][40];  // stride 40 shorts = 80B: 16B-aligned rows, 2-way banks (free)
  __shared__ short Ws[64][40];
  const int tid = threadIdx.x;
  const int lane = tid & 63, wv = tid >> 6;
  const int quad = lane >> 4, l15 = lane & 15;
  const int m0 = blockIdx.y * 64, n0 = blockIdx.x * 64;
  const int srow = tid >> 2, kq = tid & 3;
  const int am = m0 + srow;
  const TIN* Arow = A + (size_t)(am & 31) * kS * K + (size_t)(am >> 5) * K;
  const float* Wrow = W + (size_t)(n0 + srow) * K;

  f32x4 acc[4] = {};

  for (int k0 = 0; k0 < K; k0 += 32) {
    float av[8], wvv[8];
    load8(Arow + k0 + kq * 8, av);
    load8(Wrow + k0 + kq * 8, wvv);
    __syncthreads();  // previous iteration's LDS reads complete
#pragma unroll
    for (int j = 0; j < 8; ++j) As[srow][kq * 8 + j] = f2bf(av[j]);
#pragma unroll
    for (int j = 0; j < 8; ++j) Ws[srow][kq * 8 + j] = f2bf(wvv[j]);
    __syncthreads();
    const bf16x8 bf = *(const bf16x8*)&Ws[wv * 16 + l15][quad * 8];
#pragma unroll
    for (int mt = 0; mt < 4; ++mt) {
      const bf16x8 af = *(const bf16x8*)&As[mt * 16 + l15][quad * 8];
      acc[mt] = __builtin_amdgcn_mfma_f32_16x16x32_bf16(af, bf, acc[mt], 0, 0, 0);
    }
  }
  const int col = n0 + wv * 16 + l15;
  const float bias = b_ih[col] + (col < 512 ? b_hh[col] : 0.0f);
#pragma unroll
  for (int mt = 0; mt < 4; ++mt) {
#pragma unroll
    for (int r = 0; r < 4; ++r) {
      const int m = m0 + mt * 16 + quad * 4 + r;
      gx[(size_t)m * kG + col] = (_Float16)(acc[mt][r] + bias);
    }
  }
}

union Frag8 {
  bf16x8 v;
  uint2 u2[2];
};

// One WG per (dir, batch-half): 16 batch rows, 512 threads (8 waves).
// Wave w owns hidden cols [w*32, w*32+32). W_hh B-frags: kb 0..6 register-resident,
// kb 7 (k=224..256) staged in LDS. h carried fp32 in regs + bf16 copy in LDS for A-frags.
template <typename TOUT>
__global__ __launch_bounds__(512, 2) void gru_scan(
    const _Float16* __restrict__ gx,  // [S*32][768] (incl. b_ih + b_hh for r,z)
    const float* __restrict__ W_hh,   // [768][256]
    const float* __restrict__ b_hh,   // [768] (only n-part used here)
    TOUT* __restrict__ out,           // [B][S][512], cols dir*256 ..
    float* __restrict__ hn) {         // [2][32][256] for this layer
  __shared__ short hlds[16][264];  // stride 264: 16B-aligned rows, 2-way banks
  __shared__ short wlds[768][36];  // kb=7 slice; stride 36 shorts = 72B (8B-aligned, b64 reads)

  const int tid = threadIdx.x;
  const int lane = tid & 63;
  const int w = tid >> 6;
  const int quad = lane >> 4, l15 = lane & 15;
  const int dir = blockIdx.x & 1;
  const int bbase = (blockIdx.x >> 1) * 16;

  for (int i = tid; i < 16 * 264; i += 512) (&hlds[0][0])[i] = 0;

  {  // stage W_hh[:, 224:256] -> LDS (bf16)
    const int kq = tid & 3, rb = tid >> 2;
#pragma unroll
    for (int j = 0; j < 6; ++j) {
      const int row = rb + j * 128;
      float v[8];
      load8(W_hh + (size_t)row * kH + 224 + kq * 8, v);
#pragma unroll
      for (int e = 0; e < 8; ++e) wlds[row][kq * 8 + e] = f2bf(v[e]);
    }
  }

  const int colH0 = w * 32 + l15;
  bf16x8 Bf[3][2][7];
#pragma unroll
  for (int g3 = 0; g3 < 3; ++g3)
#pragma unroll
    for (int nt = 0; nt < 2; ++nt)
#pragma unroll
      for (int kb = 0; kb < 7; ++kb) {
        const int row = g3 * 256 + colH0 + nt * 16;
        float v[8];
        load8(W_hh + (size_t)row * kH + kb * 32 + quad * 8, v);
        bf16x8 f;
#pragma unroll
        for (int e = 0; e < 8; ++e) f[e] = f2bf(v[e]);
        Bf[g3][nt][kb] = f;
      }

  const float bhn[2] = {b_hh[512 + colH0], b_hh[512 + colH0 + 16]};
  float hprev[8] = {0, 0, 0, 0, 0, 0, 0, 0};

  __syncthreads();

  for (int i = 0; i < kS; ++i) {
    const int t = dir ? (kS - 1 - i) : i;
    const _Float16* gxt = gx + (size_t)t * (kB * kG);

    // issue gx(t) loads up front; latency hidden under the MFMA phase
    _Float16 gxv[3][2][4];
#pragma unroll
    for (int g3 = 0; g3 < 3; ++g3)
#pragma unroll
      for (int nt = 0; nt < 2; ++nt)
#pragma unroll
        for (int r = 0; r < 4; ++r)
          gxv[g3][nt][r] =
              gxt[(size_t)(bbase + quad * 4 + r) * kG + g3 * 256 + colH0 + nt * 16];

    f32x4 C[3][2] = {};
#pragma unroll
    for (int kb = 0; kb < 8; ++kb) {
      const bf16x8 af = *(const bf16x8*)&hlds[l15][kb * 32 + quad * 8];
      if (kb < 7) {
#pragma unroll
        for (int g3 = 0; g3 < 3; ++g3)
#pragma unroll
          for (int nt = 0; nt < 2; ++nt)
            C[g3][nt] = __builtin_amdgcn_mfma_f32_16x16x32_bf16(
                af, Bf[g3][nt][kb], C[g3][nt], 0, 0, 0);
      } else {
#pragma unroll
        for (int g3 = 0; g3 < 3; ++g3)
#pragma unroll
          for (int nt = 0; nt < 2; ++nt) {
            Frag8 bf;
            const int row = g3 * 256 + colH0 + nt * 16;
            bf.u2[0] = *(const uint2*)&wlds[row][quad * 8];
            bf.u2[1] = *(const uint2*)&wlds[row][quad * 8 + 4];
            C[g3][nt] = __builtin_amdgcn_mfma_f32_16x16x32_bf16(
                af, bf.v, C[g3][nt], 0, 0, 0);
          }
      }
    }
    __syncthreads();  // all hlds reads done -> safe to overwrite

#pragma unroll
    for (int nt = 0; nt < 2; ++nt) {
#pragma unroll
      for (int r = 0; r < 4; ++r) {
        const float xr = (float)gxv[0][nt][r];
        const float xz = (float)gxv[1][nt][r];
        const float xn = (float)gxv[2][nt][r];
        const float rr = fast_sigmoid(xr + C[0][nt][r]);
        const float zz = fast_sigmoid(xz + C[1][nt][r]);
        const float nn = fast_tanh(xn + rr * (C[2][nt][r] + bhn[nt]));
        const int e = nt * 4 + r;
        const float h = nn + zz * (hprev[e] - nn);
        hprev[e] = h;
        const int b = bbase + quad * 4 + r;
        out[((size_t)b * kS + t) * 512 + dir * 256 + colH0 + nt * 16] = (TOUT)h;
        hlds[quad * 4 + r][colH0 + nt * 16] = f2bf(h);
      }
    }
    __syncthreads();  // h writes visible
  }

#pragma unroll
  for (int nt = 0; nt < 2; ++nt)
#pragma unroll
    for (int r = 0; r < 4; ++r)
      hn[(size_t)(dir * kB + bbase + quad * 4 + r) * kH + colH0 + nt * 16] =
          hprev[nt * 4 + r];
}

extern "C" void kernel_launch(void* const* d_in, const int* in_sizes, int n_in,
                              void* d_out, int out_size, void* d_ws, size_t ws_size,
                              hipStream_t stream) {
  const float* x     = (const float*)d_in[0];  // [B][S][256]
  const float* W_ih0 = (const float*)d_in[1];  // [768][256]
  const float* W_hh0 = (const float*)d_in[2];  // [768][256]
  const float* b_ih0 = (const float*)d_in[3];
  const float* b_hh0 = (const float*)d_in[4];
  const float* W_ih1 = (const float*)d_in[5];  // [768][512]
  const float* W_hh1 = (const float*)d_in[6];  // [768][256]
  const float* b_ih1 = (const float*)d_in[7];
  const float* b_hh1 = (const float*)d_in[8];

  float* out1 = (float*)d_out;                       // [B][S][512]
  float* hn = out1 + (size_t)kB * kS * 512;          // [4][B][H]

  _Float16* gxb  = (_Float16*)d_ws;                                  // [S*32][768] fp16
  _Float16* out0 = (_Float16*)((char*)d_ws + (size_t)kS * kB * kG * 2);  // [B][S][512] fp16

  dim3 ggrid(kG / 64, (kS * kB) / 64);

  // Layer 0
  gemm_gx<float><<<ggrid, 256, 0, stream>>>(x, W_ih0, b_ih0, b_hh0, gxb, 256);
  gru_scan<_Float16><<<dim3(4), 512, 0, stream>>>(gxb, W_hh0, b_hh0, out0, hn);
  // Layer 1
  gemm_gx<_Float16><<<ggrid, 256, 0, stream>>>(out0, W_ih1, b_ih1, b_hh1, gxb, 512);
  gru_scan<float><<<dim3(4), 512, 0, stream>>>(gxb, W_hh1, b_hh1, out1, hn + 2 * kB * kH);
}

// Round 2
// 7831.889 us; speedup vs baseline: 1.2617x; 1.2617x over previous
//
#include <hip/hip_runtime.h>

typedef __attribute__((ext_vector_type(4))) float f32x4;
typedef __attribute__((ext_vector_type(8))) short bf16x8;
typedef __attribute__((ext_vector_type(4))) _Float16 f16x4;

constexpr int kB = 32;    // batch
constexpr int kS = 2048;  // seq len
constexpr int kH = 256;   // hidden
constexpr int kG = 768;   // 3*H

__device__ __forceinline__ short f2bf(float f) {
  unsigned u = __builtin_bit_cast(unsigned, f);
  u += 0x7fffu + ((u >> 16) & 1u);  // RNE
  return (short)(u >> 16);
}

__device__ __forceinline__ float fast_sigmoid(float x) {
  float e = __builtin_amdgcn_exp2f(x * 1.4426950408889634f);
  return e * __builtin_amdgcn_rcpf(1.0f + e);
}
__device__ __forceinline__ float fast_tanh(float x) {
  float e = __builtin_amdgcn_exp2f(x * 2.8853900817779268f);  // e^(2x)
  return 1.0f - 2.0f * __builtin_amdgcn_rcpf(1.0f + e);
}

__device__ __forceinline__ void load8(const float* p, float v[8]) {
  const float4 a = *(const float4*)p;
  const float4 b = *(const float4*)(p + 4);
  v[0] = a.x; v[1] = a.y; v[2] = a.z; v[3] = a.w;
  v[4] = b.x; v[5] = b.y; v[6] = b.z; v[7] = b.w;
}

// gx[t][g][b] = sum_k A[b][t][k] * W[g][k] + b_ih[g] + (g<512 ? b_hh[g] : 0)
// LAYER 0: A = fp32 [B][S][256].  LAYER 1: A = bf16 out0 [S][2][32][256] (K=512).
template <int LAYER>
__global__ __launch_bounds__(256) void gemm_gx(
    const void* __restrict__ Av, const float* __restrict__ W,
    const float* __restrict__ b_ih, const float* __restrict__ b_hh,
    _Float16* __restrict__ gx) {
  constexpr int K = (LAYER == 0) ? 256 : 512;
  __shared__ short As[64][40];  // stride 40 shorts = 80B: 16B-aligned rows, 2-way banks (free)
  __shared__ short Ws[64][40];
  const int tid = threadIdx.x;
  const int lane = tid & 63, wv = tid >> 6;
  const int quad = lane >> 4, l15 = lane & 15;
  const int m0 = blockIdx.y * 64, n0 = blockIdx.x * 64;
  const int srow = tid >> 2, kq = tid & 3;
  const int am = m0 + srow;
  const int b = am & 31, s = am >> 5;
  const float* Wrow = W + (size_t)(n0 + srow) * K;
  const float* Af = (const float*)Av + ((size_t)b * kS + s) * 256;
  const short* Ab = (const short*)Av + ((size_t)s * 64 + b) * 256;  // [s][dir][32][256]

  f32x4 acc[4] = {};

  for (int k0 = 0; k0 < K; k0 += 32) {
    const int k = k0 + kq * 8;
    short avs[8];
    if constexpr (LAYER == 0) {
      float v[8];
      load8(Af + k, v);
#pragma unroll
      for (int j = 0; j < 8; ++j) avs[j] = f2bf(v[j]);
    } else {
      *(uint4*)avs = *(const uint4*)(Ab + (size_t)(k >> 8) * 8192 + (k & 255));
    }
    float wv8[8];
    load8(Wrow + k, wv8);
    __syncthreads();  // previous iteration's LDS reads complete
#pragma unroll
    for (int j = 0; j < 8; ++j) As[srow][kq * 8 + j] = avs[j];
#pragma unroll
    for (int j = 0; j < 8; ++j) Ws[srow][kq * 8 + j] = f2bf(wv8[j]);
    __syncthreads();
    const bf16x8 bf = *(const bf16x8*)&Ws[wv * 16 + l15][quad * 8];
#pragma unroll
    for (int mt = 0; mt < 4; ++mt) {
      const bf16x8 af = *(const bf16x8*)&As[mt * 16 + l15][quad * 8];
      acc[mt] = __builtin_amdgcn_mfma_f32_16x16x32_bf16(af, bf, acc[mt], 0, 0, 0);
    }
  }
  const int col = n0 + wv * 16 + l15;
  const float bias = b_ih[col] + (col < 512 ? b_hh[col] : 0.0f);
#pragma unroll
  for (int mt = 0; mt < 4; ++mt) {
#pragma unroll
    for (int r = 0; r < 4; ++r) {
      const int m = m0 + mt * 16 + quad * 4 + r;
      gx[((size_t)(m >> 5) * kG + col) * 32 + (m & 31)] = (_Float16)(acc[mt][r] + bias);
    }
  }
}

union Frag8 {
  bf16x8 v;
  uint2 u2[2];
};

// One WG per (dir, batch-half): 16 batch rows, 512 threads (8 waves).
// Gate-major MFMA chains (r, n, z) so r/n gate VALU overlaps the z-chain MFMAs.
// LAYER 0: out = bf16 [S][2][32][256] written via hlds b128 read + dwordx4 store.
// LAYER 1: out = fp32 [B][S][512] scalar stores (full precision).
template <int LAYER>
__global__ __launch_bounds__(512, 2) void gru_scan(
    const _Float16* __restrict__ gx,  // [S][768][32] (incl. b_ih + b_hh for r,z)
    const float* __restrict__ W_hh,   // [768][256]
    const float* __restrict__ b_hh,   // [768] (only n-part used here)
    void* __restrict__ outv,
    float* __restrict__ hn) {         // [2][32][256] slab for this layer
  __shared__ short hlds[16][264];  // stride 264: 16B-aligned rows, 2-way banks (free)
  __shared__ short wlds[768][36];  // kb=7 slice; stride 36 shorts = 72B (8B-aligned b64)

  const int tid = threadIdx.x;
  const int lane = tid & 63;
  const int w = tid >> 6;
  const int quad = lane >> 4, l15 = lane & 15;
  const int dir = blockIdx.x & 1;
  const int bbase = (blockIdx.x >> 1) * 16;

  for (int i = tid; i < 16 * 264; i += 512) (&hlds[0][0])[i] = 0;

  {  // stage W_hh[:, 224:256] -> LDS (bf16)
    const int kq = tid & 3, rb = tid >> 2;
#pragma unroll
    for (int j = 0; j < 6; ++j) {
      const int row = rb + j * 128;
      float v[8];
      load8(W_hh + (size_t)row * kH + 224 + kq * 8, v);
#pragma unroll
      for (int e = 0; e < 8; ++e) wlds[row][kq * 8 + e] = f2bf(v[e]);
    }
  }

  const int colH0 = w * 32 + l15;
  bf16x8 Bf[3][2][7];  // kb 0..6 register-resident
#pragma unroll
  for (int g3 = 0; g3 < 3; ++g3)
#pragma unroll
    for (int nt = 0; nt < 2; ++nt)
#pragma unroll
      for (int kb = 0; kb < 7; ++kb) {
        const int row = g3 * 256 + colH0 + nt * 16;
        float v[8];
        load8(W_hh + (size_t)row * kH + kb * 32 + quad * 8, v);
        bf16x8 f;
#pragma unroll
        for (int e = 0; e < 8; ++e) f[e] = f2bf(v[e]);
        Bf[g3][nt][kb] = f;
      }

  const float bhn[2] = {b_hh[512 + colH0], b_hh[512 + colH0 + 16]};
  float hprev[8] = {0, 0, 0, 0, 0, 0, 0, 0};

  short* out0 = (short*)outv;
  float* out1 = (float*)outv;

  __syncthreads();

  for (int i = 0; i < kS; ++i) {
    const int t = dir ? (kS - 1 - i) : i;
    const _Float16* gxt = gx + (size_t)t * (kG * 32);

    // 6x dwordx2 gx loads; latency hidden under the r/n MFMA chains
    f16x4 gxv[3][2];
#pragma unroll
    for (int g3 = 0; g3 < 3; ++g3)
#pragma unroll
      for (int nt = 0; nt < 2; ++nt)
        gxv[g3][nt] = *(const f16x4*)(gxt + (size_t)(g3 * 256 + colH0 + nt * 16) * 32 +
                                      bbase + quad * 4);

    f32x4 C0[2] = {}, C1[2] = {}, C2[2] = {};

#define CHAIN(G3, CC)                                                              \
  {                                                                                \
    _Pragma("unroll") for (int kb = 0; kb < 7; ++kb) {                             \
      const bf16x8 af = *(const bf16x8*)&hlds[l15][kb * 32 + quad * 8];            \
      _Pragma("unroll") for (int nt = 0; nt < 2; ++nt) CC[nt] =                    \
          __builtin_amdgcn_mfma_f32_16x16x32_bf16(af, Bf[G3][nt][kb], CC[nt], 0, 0, 0); \
    }                                                                              \
    const bf16x8 af7 = *(const bf16x8*)&hlds[l15][224 + quad * 8];                 \
    _Pragma("unroll") for (int nt = 0; nt < 2; ++nt) {                             \
      Frag8 bf;                                                                    \
      const int row = G3 * 256 + colH0 + nt * 16;                                  \
      bf.u2[0] = *(const uint2*)&wlds[row][quad * 8];                              \
      bf.u2[1] = *(const uint2*)&wlds[row][quad * 8 + 4];                          \
      CC[nt] = __builtin_amdgcn_mfma_f32_16x16x32_bf16(af7, bf.v, CC[nt], 0, 0, 0); \
    }                                                                              \
  }

    CHAIN(0, C0)  // r-gate accumulators first
    CHAIN(2, C2)  // n-gate

    float rr[2][4];  // r sigmoids overlap the z-chain below
#pragma unroll
    for (int nt = 0; nt < 2; ++nt)
#pragma unroll
      for (int r = 0; r < 4; ++r)
        rr[nt][r] = fast_sigmoid((float)gxv[0][nt][r] + C0[nt][r]);

    CHAIN(1, C1)  // z-gate last

    float nn[2][4];
#pragma unroll
    for (int nt = 0; nt < 2; ++nt)
#pragma unroll
      for (int r = 0; r < 4; ++r)
        nn[nt][r] = fast_tanh((float)gxv[2][nt][r] + rr[nt][r] * (C2[nt][r] + bhn[nt]));

    __syncthreads();  // barrier-1: all hlds A-frag reads complete

#pragma unroll
    for (int nt = 0; nt < 2; ++nt) {
#pragma unroll
      for (int r = 0; r < 4; ++r) {
        const float zz = fast_sigmoid((float)gxv[1][nt][r] + C1[nt][r]);
        const int e = nt * 4 + r;
        const float h = nn[nt][r] + zz * (hprev[e] - nn[nt][r]);
        hprev[e] = h;
        hlds[quad * 4 + r][colH0 + nt * 16] = f2bf(h);
        if constexpr (LAYER == 1) {
          out1[((size_t)(bbase + quad * 4 + r) * kS + t) * 512 + dir * 256 + colH0 +
               nt * 16] = h;
        }
      }
    }
    __syncthreads();  // barrier-2: h(t) visible

    if constexpr (LAYER == 0) {  // vectorized bf16 out0 store via hlds
      const int srow = tid >> 5, schunk = tid & 31;
      *(uint4*)(out0 + (((size_t)t * 2 + dir) * 32 + bbase + srow) * 256 + schunk * 8) =
          *(const uint4*)&hlds[srow][schunk * 8];
    }
  }
#undef CHAIN

#pragma unroll
  for (int nt = 0; nt < 2; ++nt)
#pragma unroll
    for (int r = 0; r < 4; ++r)
      hn[(size_t)(dir * kB + bbase + quad * 4 + r) * kH + colH0 + nt * 16] =
          hprev[nt * 4 + r];
}

extern "C" void kernel_launch(void* const* d_in, const int* in_sizes, int n_in,
                              void* d_out, int out_size, void* d_ws, size_t ws_size,
                              hipStream_t stream) {
  const float* x     = (const float*)d_in[0];  // [B][S][256]
  const float* W_ih0 = (const float*)d_in[1];  // [768][256]
  const float* W_hh0 = (const float*)d_in[2];  // [768][256]
  const float* b_ih0 = (const float*)d_in[3];
  const float* b_hh0 = (const float*)d_in[4];
  const float* W_ih1 = (const float*)d_in[5];  // [768][512]
  const float* W_hh1 = (const float*)d_in[6];  // [768][256]
  const float* b_ih1 = (const float*)d_in[7];
  const float* b_hh1 = (const float*)d_in[8];

  float* out1 = (float*)d_out;                  // [B][S][512]
  float* hn = out1 + (size_t)kB * kS * 512;     // [4][B][H]

  _Float16* gxb = (_Float16*)d_ws;  // [S][768][32] fp16 (96 MB)
  short* out0 = (short*)((char*)d_ws + (size_t)kS * kB * kG * 2);  // bf16 [S][2][32][256] (64 MB)

  dim3 ggrid(kG / 64, (kS * kB) / 64);

  // Layer 0
  gemm_gx<0><<<ggrid, 256, 0, stream>>>(x, W_ih0, b_ih0, b_hh0, gxb);
  gru_scan<0><<<dim3(4), 512, 0, stream>>>(gxb, W_hh0, b_hh0, out0, hn);
  // Layer 1
  gemm_gx<1><<<ggrid, 256, 0, stream>>>(out0, W_ih1, b_ih1, b_hh1, gxb);
  gru_scan<1><<<dim3(4), 512, 0, stream>>>(gxb, W_hh1, b_hh1, out1, hn + 2 * kB * kH);
}